// Round 3
// baseline (183.082 us; speedup 1.0000x reference)
//
#include <hip/hip_runtime.h>
#include <hip/hip_bf16.h>
#include <math.h>

#define D_DIM 2048
#define L_DIM 64
#define E_NUM 64
#define H_DIM 64

typedef float f32x4_t __attribute__((ext_vector_type(4)));
typedef __bf16 bf16x8_t __attribute__((ext_vector_type(8)));

// ---------------- workspace layout (bytes) ----------------
// WS_UPART: 512*2048 f32 partial sums of u      (4 MB)
// WS_U:     2048 f32 u = x^T wout               (8 KB)
// WS_V:     64 f32 v = Wg_in u
// WS_META:  sel[2] (int) + g[2] (float)
// WS_WB:    128*2048 bf16 selected expert weights (512 KB)
// WS_XB:    8192*2048 bf16 pre-converted x       (32 MB)
// WS_PART:  4*8192*128 f32 split-K GEMM partials (16 MB)
#define WS_UPART 0u
#define WS_U     (512u * 2048u * 4u)
#define WS_V     (WS_U + 2048u * 4u)
#define WS_META  (WS_V + 256u)
#define WS_WB    (WS_META + 64u)
#define WS_XB    (WS_WB + 128u * 2048u * 2u)
#define WS_PART  (WS_XB + 8192u * 2048u * 2u)

// ---------------- kernel 1: u_part + bf16 cast of x ----------------
// u_part[c][d] = sum_{s in 16-row chunk c} x[s,d]*wout[s]; also xb = bf16(x).
__global__ void k_upart(const float* __restrict__ x, const float* __restrict__ wout,
                        float* __restrict__ upart, __hip_bfloat16* __restrict__ xb) {
  const int d8 = threadIdx.x * 8;       // 256 threads x 8 cols = 2048
  const int s0 = blockIdx.x * 16;       // 512 blocks x 16 rows = 8192
  float a0 = 0.f, a1 = 0.f, a2 = 0.f, a3 = 0.f;
  float a4 = 0.f, a5 = 0.f, a6 = 0.f, a7 = 0.f;
  for (int i = 0; i < 16; ++i) {
    const size_t row = (size_t)(s0 + i);
    const float w = wout[s0 + i];
    const float4 pa = *reinterpret_cast<const float4*>(x + row * D_DIM + d8);
    const float4 pb = *reinterpret_cast<const float4*>(x + row * D_DIM + d8 + 4);
    a0 += pa.x * w; a1 += pa.y * w; a2 += pa.z * w; a3 += pa.w * w;
    a4 += pb.x * w; a5 += pb.y * w; a6 += pb.z * w; a7 += pb.w * w;
    union { __hip_bfloat16 h[8]; uint4 u; } pk;
    pk.h[0] = __float2bfloat16(pa.x); pk.h[1] = __float2bfloat16(pa.y);
    pk.h[2] = __float2bfloat16(pa.z); pk.h[3] = __float2bfloat16(pa.w);
    pk.h[4] = __float2bfloat16(pb.x); pk.h[5] = __float2bfloat16(pb.y);
    pk.h[6] = __float2bfloat16(pb.z); pk.h[7] = __float2bfloat16(pb.w);
    *reinterpret_cast<uint4*>(xb + row * D_DIM + d8) = pk.u;
  }
  float* up = upart + (size_t)blockIdx.x * D_DIM + d8;
  *reinterpret_cast<float4*>(up)     = make_float4(a0, a1, a2, a3);
  *reinterpret_cast<float4*>(up + 4) = make_float4(a4, a5, a6, a7);
}

// ---------------- kernel 1b: u[d] = sum_c u_part[c][d] ----------------
__global__ void k_ufinish(const float* __restrict__ upart, float* __restrict__ u) {
  const int d = blockIdx.x * 256 + threadIdx.x;  // grid 8 x 256
  float s = 0.f;
#pragma unroll 8
  for (int c = 0; c < 512; ++c) s += upart[(size_t)c * D_DIM + d];
  u[d] = s;
}

// ---------------- kernel 2a: v[h] = Wg_in[h,:] . u ----------------
__global__ void k_v(const float* __restrict__ wg_in, const float* __restrict__ u,
                    float* __restrict__ v) {
  const int h = blockIdx.x;  // 64 blocks
  const int t = threadIdx.x; // 256 threads
  const float4* wr = reinterpret_cast<const float4*>(wg_in + (size_t)h * D_DIM);
  const float4* ur = reinterpret_cast<const float4*>(u);
  float s = 0.f;
#pragma unroll
  for (int i = t; i < 512; i += 256) {
    const float4 a = wr[i];
    const float4 b = ur[i];
    s += a.x * b.x + a.y * b.y + a.z * b.z + a.w * b.w;
  }
  __shared__ float red[4];
#pragma unroll
  for (int off = 32; off; off >>= 1) s += __shfl_down(s, off, 64);
  if ((t & 63) == 0) red[t >> 6] = s;
  __syncthreads();
  if (t == 0) v[h] = red[0] + red[1] + red[2] + red[3];
}

// ---------------- kernel 2b: scores, top-2, softmax ----------------
__global__ void k_gate(const float* __restrict__ wg_lin, const float* __restrict__ v,
                       int* __restrict__ sel, float* __restrict__ g) {
  __shared__ float vv[H_DIM];
  __shared__ float sc[E_NUM];
  const int t = threadIdx.x;  // 64 threads
  vv[t] = v[t];
  __syncthreads();
  float s = 0.f;
#pragma unroll 8
  for (int hh = 0; hh < H_DIM; ++hh) s += wg_lin[t * H_DIM + hh] * vv[hh];
  sc[t] = s;
  __syncthreads();
  if (t == 0) {
    int b1 = 0; float m1 = sc[0];
    for (int e = 1; e < E_NUM; ++e) { if (sc[e] > m1) { m1 = sc[e]; b1 = e; } }
    int b2 = -1; float m2 = -3.4e38f;
    for (int e = 0; e < E_NUM; ++e) {
      if (e != b1 && sc[e] > m2) { m2 = sc[e]; b2 = e; }
    }
    const float e2 = expf(m2 - m1);
    const float g0 = 1.0f / (1.0f + e2);
    sel[0] = b1; sel[1] = b2;
    g[0] = g0; g[1] = 1.0f - g0;
  }
}

// ---------------- kernel 2c: cast selected experts to bf16 ----------------
__global__ void k_wb(const float* __restrict__ we, const int* __restrict__ sel,
                     __hip_bfloat16* __restrict__ wb) {
  const int n = blockIdx.x;         // 128 rows = 2 experts x 64
  const int e = sel[n >> 6];
  const int l = n & 63;
  const float* src = we + ((size_t)e * L_DIM + l) * D_DIM;
  const int t = threadIdx.x;        // 256 threads, 8 elems each
  const float4 a = reinterpret_cast<const float4*>(src)[2 * t];
  const float4 b = reinterpret_cast<const float4*>(src)[2 * t + 1];
  union { __hip_bfloat16 h[8]; uint4 u; } pk;
  pk.h[0] = __float2bfloat16(a.x); pk.h[1] = __float2bfloat16(a.y);
  pk.h[2] = __float2bfloat16(a.z); pk.h[3] = __float2bfloat16(a.w);
  pk.h[4] = __float2bfloat16(b.x); pk.h[5] = __float2bfloat16(b.y);
  pk.h[6] = __float2bfloat16(b.z); pk.h[7] = __float2bfloat16(b.w);
  reinterpret_cast<uint4*>(wb + (size_t)n * D_DIM)[t] = pk.u;
}

// ---------------- kernel 3: bf16 MFMA GEMM -> f32 partials ----------------
// Grid (64, 4): blockIdx.x = M-tile (128 rows), blockIdx.y = K-chunk (512).
// 512 threads = 8 waves (2 Mw x 4 Nw); wave tile 64x32; 8 K-steps of BK=64.
// Double-buffered LDS (2 x [A 16KB | B 16KB]); stage(next) issued BEFORE
// compute(cur), single barrier per step (T3-minimum pipeline).
// Per-CU staged bytes: 256 KB (vs 640 KB in the 32-row-tile version).
// Both tiles: row-major 128B rows, 16B k-chunks XOR-swizzled by (row&7);
// swizzle applied on the GLOBAL source address, LDS dest linear (m104 rule).
__device__ __forceinline__ void async_ld16(const void* gp, void* lp) {
  __builtin_amdgcn_global_load_lds(
      (const __attribute__((address_space(1))) unsigned int*)gp,
      (__attribute__((address_space(3))) unsigned int*)lp, 16, 0, 0);
}

__device__ __forceinline__ float gelu_f(float v) {
  return 0.5f * v * (1.0f + erff(v * 0.70710678118654752440f));
}

__global__ __launch_bounds__(512) void k_moe_gemm(
    const __hip_bfloat16* __restrict__ xb, const __hip_bfloat16* __restrict__ wb,
    float* __restrict__ part) {
  __shared__ __align__(16) unsigned char lds[2][32768];  // 64 KB

  const int tid = threadIdx.x;
  const int w = tid >> 6, lane = tid & 63;
  const int wm = w >> 2, wn = w & 3;           // wave M-slot (0..1), N-slot (0..3)
  const int m0 = blockIdx.x * 128;
  const int kg = blockIdx.y;                   // K-chunk 0..3
  const int kbase = kg * 512;
  const int fr = lane & 15, fq = lane >> 4;

  // staging chunk assignment: 1024 16B chunks per tile, 2 per thread,
  // lane-consecutive within each phase (global_load_lds dest = base+lane*16).
  int sr[2], skc[2];
#pragma unroll
  for (int ph = 0; ph < 2; ++ph) {
    const int c = ph * 512 + tid;
    sr[ph] = c >> 3;
    skc[ph] = (c & 7) ^ (sr[ph] & 7);
  }

  f32x4_t acc[4][2];
#pragma unroll
  for (int mf = 0; mf < 4; ++mf)
#pragma unroll
    for (int nf = 0; nf < 2; ++nf) acc[mf][nf] = (f32x4_t){0.f, 0.f, 0.f, 0.f};

  auto stage = [&](int buf, int kk) {
    const int koff = kbase + kk * 64;
#pragma unroll
    for (int ph = 0; ph < 2; ++ph) {
      const int c = ph * 512 + tid;
      async_ld16(xb + (size_t)(m0 + sr[ph]) * D_DIM + koff + skc[ph] * 8,
                 &lds[buf][c * 16]);
      async_ld16(wb + (size_t)sr[ph] * D_DIM + koff + skc[ph] * 8,
                 &lds[buf][16384 + c * 16]);
    }
  };

  stage(0, 0);
  __syncthreads();
  for (int kk = 0; kk < 8; ++kk) {
    const int cur = kk & 1;
    if (kk < 7) stage(cur ^ 1, kk + 1);   // loads fly during compute below
    const unsigned char* ldsA = lds[cur];
    const unsigned char* ldsB = lds[cur] + 16384;
    union fragu { uint4 u; bf16x8_t v; };
    fragu af[4][2], bf_[2][2];
#pragma unroll
    for (int mf = 0; mf < 4; ++mf)
#pragma unroll
      for (int ks = 0; ks < 2; ++ks) {
        const int ar = wm * 64 + mf * 16 + fr;
        const int kq = ks * 4 + fq;
        af[mf][ks].u = *reinterpret_cast<const uint4*>(
            ldsA + ar * 128 + ((kq ^ (ar & 7)) * 16));
      }
#pragma unroll
    for (int nf = 0; nf < 2; ++nf)
#pragma unroll
      for (int ks = 0; ks < 2; ++ks) {
        const int br = wn * 32 + nf * 16 + fr;
        const int kq = ks * 4 + fq;
        bf_[nf][ks].u = *reinterpret_cast<const uint4*>(
            ldsB + br * 128 + ((kq ^ (br & 7)) * 16));
      }
#pragma unroll
    for (int mf = 0; mf < 4; ++mf)
#pragma unroll
      for (int nf = 0; nf < 2; ++nf) {
        acc[mf][nf] = __builtin_amdgcn_mfma_f32_16x16x32_bf16(
            af[mf][0].v, bf_[nf][0].v, acc[mf][nf], 0, 0, 0);
        acc[mf][nf] = __builtin_amdgcn_mfma_f32_16x16x32_bf16(
            af[mf][1].v, bf_[nf][1].v, acc[mf][nf], 0, 0, 0);
      }
    __syncthreads();   // drains vmcnt (next buf ready) + protects cur for restage
  }

  // ---- epilogue: z[128][128] f32 overlays both LDS buffers (64 KB) ----
  float* z = reinterpret_cast<float*>(lds);
#pragma unroll
  for (int mf = 0; mf < 4; ++mf)
#pragma unroll
    for (int nf = 0; nf < 2; ++nf)
#pragma unroll
      for (int reg = 0; reg < 4; ++reg)
        z[(wm * 64 + mf * 16 + fq * 4 + reg) * 128 + wn * 32 + nf * 16 + fr] =
            acc[mf][nf][reg];
  __syncthreads();
#pragma unroll
  for (int p = 0; p < 8; ++p) {
    const int idx = p * 512 + tid;
    const int r = idx >> 5, c4 = (idx & 31) * 4;
    *reinterpret_cast<f32x4_t*>(part + ((size_t)kg * 8192 + m0 + r) * 128 + c4) =
        *reinterpret_cast<const f32x4_t*>(z + r * 128 + c4);
  }
}

// ---------------- kernel 4: reduce partials + normalize + gelu + combine ----
__global__ __launch_bounds__(256) void k_finish(const float* __restrict__ part,
                                                const float* __restrict__ gw,
                                                float* __restrict__ out) {
  __shared__ float z[32 * 132];
  __shared__ float ps[32 * 8];
  const int tid = threadIdx.x;
  const int m0 = blockIdx.x * 32;   // 256 blocks
  const float g0 = gw[0], g1 = gw[1];
  const size_t KSTRIDE = (size_t)8192 * 128;
#pragma unroll
  for (int p = 0; p < 4; ++p) {
    const int idx = p * 256 + tid;
    const int r = idx >> 5, c4 = (idx & 31) * 4;
    const float* pp = part + ((size_t)(m0 + r)) * 128 + c4;
    const f32x4_t s = *reinterpret_cast<const f32x4_t*>(pp)
                    + *reinterpret_cast<const f32x4_t*>(pp + KSTRIDE)
                    + *reinterpret_cast<const f32x4_t*>(pp + 2 * KSTRIDE)
                    + *reinterpret_cast<const f32x4_t*>(pp + 3 * KSTRIDE);
    z[r * 132 + c4 + 0] = s[0];
    z[r * 132 + c4 + 1] = s[1];
    z[r * 132 + c4 + 2] = s[2];
    z[r * 132 + c4 + 3] = s[3];
  }
  __syncthreads();
  {
    const int r = tid >> 3, seg = tid & 7;
    float s = 0.f;
#pragma unroll
    for (int i2 = 0; i2 < 16; ++i2) {
      const float t2 = z[r * 132 + seg * 16 + i2];
      s += t2 * t2;
    }
    ps[r * 8 + seg] = s;
  }
  __syncthreads();
  {
    const int r = tid >> 3, j = tid & 7;
    const float s0 = ps[r * 8 + 0] + ps[r * 8 + 1] + ps[r * 8 + 2] + ps[r * 8 + 3];
    const float s1 = ps[r * 8 + 4] + ps[r * 8 + 5] + ps[r * 8 + 6] + ps[r * 8 + 7];
    const float i0 = 1.0f / fmaxf(sqrtf(s0), 1e-12f);
    const float i1 = 1.0f / fmaxf(sqrtf(s1), 1e-12f);
    float o[8];
#pragma unroll
    for (int i2 = 0; i2 < 8; ++i2) {
      const int c = j * 8 + i2;
      const float za = z[r * 132 + c] * i0;
      const float zb2 = z[r * 132 + 64 + c] * i1;
      o[i2] = g0 * gelu_f(za) + g1 * gelu_f(zb2);
    }
    float4* op = reinterpret_cast<float4*>(out + (size_t)(m0 + r) * 64 + j * 8);
    op[0] = make_float4(o[0], o[1], o[2], o[3]);
    op[1] = make_float4(o[4], o[5], o[6], o[7]);
  }
}

// ---------------- launch ----------------
extern "C" void kernel_launch(void* const* d_in, const int* in_sizes, int n_in,
                              void* d_out, int out_size, void* d_ws, size_t ws_size,
                              hipStream_t stream) {
  (void)in_sizes; (void)n_in; (void)out_size; (void)ws_size;
  const float* x      = (const float*)d_in[0];
  const float* wg_in  = (const float*)d_in[1];
  const float* wg_lin = (const float*)d_in[2];
  const float* wg_out = (const float*)d_in[3];
  const float* we     = (const float*)d_in[4];
  float* out = (float*)d_out;
  char* ws = (char*)d_ws;

  float* upart = (float*)(ws + WS_UPART);
  float* u     = (float*)(ws + WS_U);
  float* v     = (float*)(ws + WS_V);
  int*   sel   = (int*)(ws + WS_META);
  float* g     = (float*)(ws + WS_META + 8);
  __hip_bfloat16* wb = (__hip_bfloat16*)(ws + WS_WB);
  __hip_bfloat16* xb = (__hip_bfloat16*)(ws + WS_XB);
  float* part = (float*)(ws + WS_PART);

  k_upart  <<<512, 256, 0, stream>>>(x, wg_out, upart, xb);
  k_ufinish<<<8, 256, 0, stream>>>(upart, u);
  k_v      <<<64, 256, 0, stream>>>(wg_in, u, v);
  k_gate   <<<1, 64, 0, stream>>>(wg_lin, v, sel, g);
  k_wb     <<<128, 256, 0, stream>>>(we, sel, wb);
  k_moe_gemm<<<dim3(64, 4), 512, 0, stream>>>(xb, wb, part);
  k_finish <<<256, 256, 0, stream>>>(part, g, out);
}